// Round 12
// baseline (116.156 us; speedup 1.0000x reference)
//
#include <hip/hip_runtime.h>

#define DEV __device__ __forceinline__

// Fixed-size value-semantics vector (pure SSA after inlining).
template <int N> struct V { float v[N == 0 ? 1 : N]; };

// General Batcher odd-even merge, by value (verified absmax=0.0 on HW, r2-r11).
template <int M, int N>
DEV V<M + N> mrg(V<M> a, V<N> b) {
    V<M + N> o;
    if constexpr (M == 0) {
#pragma unroll
        for (int i = 0; i < N; ++i) o.v[i] = b.v[i];
    } else if constexpr (N == 0) {
#pragma unroll
        for (int i = 0; i < M; ++i) o.v[i] = a.v[i];
    } else if constexpr (M == 1 && N == 1) {
        o.v[0] = fminf(a.v[0], b.v[0]);
        o.v[1] = fmaxf(a.v[0], b.v[0]);
    } else if constexpr ((M & 1) && (N & 1)) {
        constexpr int AE = (M + 1) / 2, AO = M / 2, BE = (N + 1) / 2, BO = N / 2;
        V<AE> ae; V<AO> ao; V<BE> be; V<BO> bo;
#pragma unroll
        for (int i = 0; i < AE; ++i) ae.v[i] = a.v[2 * i];
#pragma unroll
        for (int i = 0; i < AO; ++i) ao.v[i] = a.v[2 * i + 1];
#pragma unroll
        for (int i = 0; i < BE; ++i) be.v[i] = b.v[2 * i];
#pragma unroll
        for (int i = 0; i < BO; ++i) bo.v[i] = b.v[2 * i + 1];
        V<AE + BO> E = mrg<AE, BO>(ae, bo);
        V<AO + BE> O = mrg<AO, BE>(ao, be);
        constexpr int P = AE + BO;
#pragma unroll
        for (int i = 0; i < P; ++i) {
            o.v[2 * i] = fminf(E.v[i], O.v[i]);
            o.v[2 * i + 1] = fmaxf(E.v[i], O.v[i]);
        }
    } else {
        constexpr int AE = (M + 1) / 2, AO = M / 2, BE = (N + 1) / 2, BO = N / 2;
        V<AE> ae; V<AO> ao; V<BE> be; V<BO> bo;
#pragma unroll
        for (int i = 0; i < AE; ++i) ae.v[i] = a.v[2 * i];
#pragma unroll
        for (int i = 0; i < AO; ++i) ao.v[i] = a.v[2 * i + 1];
#pragma unroll
        for (int i = 0; i < BE; ++i) be.v[i] = b.v[2 * i];
#pragma unroll
        for (int i = 0; i < BO; ++i) bo.v[i] = b.v[2 * i + 1];
        V<AE + BE> E = mrg<AE, BE>(ae, be);
        V<AO + BO> O = mrg<AO, BO>(ao, bo);
        constexpr int CEn = AE + BE, COn = AO + BO;
        o.v[0] = E.v[0];
#pragma unroll
        for (int i = 0; i < COn; ++i) {
            if (i + 1 < CEn) {
                o.v[2 * i + 1] = fminf(O.v[i], E.v[i + 1]);
                o.v[2 * i + 2] = fmaxf(O.v[i], E.v[i + 1]);
            } else {
                o.v[2 * i + 1] = O.v[i];
            }
        }
    }
    return o;
}

DEV void ce(float& a, float& b) {
    float lo = fminf(a, b);
    b = fmaxf(a, b);
    a = lo;
}

// sort7 = sort3 (min3/med3/max3) + sort4 (5 CE) + merge(3,4). (verified r5-r11)
DEV V<7> sort7(V<7> x) {
    float a = x.v[0], b = x.v[1], c = x.v[2];
    V<3> s3;
    s3.v[0] = fminf(fminf(a, b), c);
    s3.v[1] = __builtin_amdgcn_fmed3f(a, b, c);
    s3.v[2] = fmaxf(fmaxf(a, b), c);
    ce(x.v[3], x.v[4]); ce(x.v[5], x.v[6]);
    ce(x.v[3], x.v[5]); ce(x.v[4], x.v[6]); ce(x.v[4], x.v[5]);
    V<4> s4;
    s4.v[0] = x.v[3]; s4.v[1] = x.v[4]; s4.v[2] = x.v[5]; s4.v[3] = x.v[6];
    return mrg<3, 4>(s3, s4);
}

// rank-24 (0-indexed) of union(A[0..41], c[0..6]): min over i+j==25 of
// max(A[i-1], c[j-1]); only A[17..24] consumed (DCE prunes). (verified r9-r11)
DEV float sel8(const V<42>& A, const V<7>& c) {
    float t0 = A.v[24];
    float t1 = fmaxf(A.v[23], c.v[0]);
    float t2 = fmaxf(A.v[22], c.v[1]);
    float t3 = fmaxf(A.v[21], c.v[2]);
    float t4 = fmaxf(A.v[20], c.v[3]);
    float t5 = fmaxf(A.v[19], c.v[4]);
    float t6 = fmaxf(A.v[18], c.v[5]);
    float t7 = fmaxf(A.v[17], c.v[6]);
    return fminf(fminf(fminf(t0, t1), fminf(t2, t3)),
                 fminf(fminf(t4, t5), fminf(t6, t7)));
}

static constexpr int W = 512, H = 512, PLANE = W * H;

// 8 px/thread: windows for px0..px7 span 14 columns c0..c13 (x0-3..x0+10),
// each sorted ONCE (1.75 sorts/px vs 2.5 at 4px/thread), and the two
// independent half-networks double per-wave ILP (r11 showed latency-bound
// at 2.6 resident waves/SIMD).
//   QA = merge(c3..c6)  -> px0..3 core;  QB = merge(c7..c10) -> px4..7 core
//   px0 = sel8(mrg(QA,P12), c0)   px1 = sel8(mrg(QA,P12), c7)
//   px2 = sel8(mrg(QA,P78), c2)   px3 = sel8(mrg(QA,P78), c9)
//   px4 = sel8(mrg(QB,P56), c4)   px5 = sel8(mrg(QB,P56), c11)
//   px6 = sel8(mrg(QB,P1112),c6)  px7 = sel8(mrg(QB,P1112),c13)
// Block = 128 threads = 2 rows (lane parity = row); cidx=((t>>1)+1)&63 puts
// all 4 border lanes in wave 1, so wave 0 skips border code via execz.
__global__ __launch_bounds__(128) __attribute__((amdgpu_waves_per_eu(1, 3)))
void median7_hardtanh_kernel(const float* __restrict__ in,
                             float* __restrict__ out) {
    // XCD-aware bijective swizzle: 6144 blocks = 8 XCDs x 768 contiguous.
    int bid = (int)blockIdx.x;
    int swz = (bid & 7) * 768 + (bid >> 3);

    int t = (int)threadIdx.x;
    int rw = t & 1;                   // row within the block's row-pair
    int cidx = ((t >> 1) + 1) & 63;   // 64 chunks/row; borders -> wave 1
    int r = swz * 2 + rw;             // global row = plane*512 + y
    int y = r & (H - 1);
    int p = r >> 9;
    const float* img = in + (size_t)p * PLANE;
    int x0 = cidx << 3;

    int rows[7];
#pragma unroll
    for (int i = 0; i < 7; ++i) {
        int tt = y + i - 3;
        tt = (tt < 0) ? -tt : tt;
        tt = (tt > H - 1) ? 2 * (H - 1) - tt : tt;
        rows[i] = tt << 9;
    }

    V<7> c0, c1, c2, c3, c4, c5, c6, c7, c8, c9, c10, c11, c12, c13;
#define SETCOLS(i, v0, v1, v2, v3, v4, v5, v6, v7, v8, v9, v10, v11, v12, v13) \
    c0.v[i] = v0; c1.v[i] = v1; c2.v[i] = v2; c3.v[i] = v3; c4.v[i] = v4;       \
    c5.v[i] = v5; c6.v[i] = v6; c7.v[i] = v7; c8.v[i] = v8; c9.v[i] = v9;       \
    c10.v[i] = v10; c11.v[i] = v11; c12.v[i] = v12; c13.v[i] = v13;

    if (cidx >= 1 && cidx <= 62) {
        // interior: 4 aligned float4/row cover cols x0-4 .. x0+11
#pragma unroll
        for (int i = 0; i < 7; ++i) {
            const float* rp = img + rows[i] + x0;
            float4 L = *reinterpret_cast<const float4*>(rp - 4);
            float4 A = *reinterpret_cast<const float4*>(rp);
            float4 B = *reinterpret_cast<const float4*>(rp + 4);
            float4 C = *reinterpret_cast<const float4*>(rp + 8);
            SETCOLS(i, L.y, L.z, L.w, A.x, A.y, A.z, A.w,
                    B.x, B.y, B.z, B.w, C.x, C.y, C.z)
        }
    } else if (cidx == 0) {
        // left border (x0=0): cols -3..10 reflect to {3,2,1,0,1,..,10}
#pragma unroll
        for (int i = 0; i < 7; ++i) {
            const float* rp = img + rows[i];
            float4 A = *reinterpret_cast<const float4*>(rp);      // 0..3
            float4 B = *reinterpret_cast<const float4*>(rp + 4);  // 4..7
            float4 C = *reinterpret_cast<const float4*>(rp + 8);  // 8..11
            SETCOLS(i, A.w, A.z, A.y, A.x, A.y, A.z, A.w,
                    B.x, B.y, B.z, B.w, C.x, C.y, C.z)
        }
    } else {
        // right border (x0=504): cols 501..514 reflect to
        // {501..511,510,509,508}
#pragma unroll
        for (int i = 0; i < 7; ++i) {
            const float* rp = img + rows[i];
            float4 B = *reinterpret_cast<const float4*>(rp + 500);  // 500..503
            float4 C = *reinterpret_cast<const float4*>(rp + 504);  // 504..507
            float4 D = *reinterpret_cast<const float4*>(rp + 508);  // 508..511
            SETCOLS(i, B.y, B.z, B.w, C.x, C.y, C.z, C.w,
                    D.x, D.y, D.z, D.w, D.z, D.y, D.x)
        }
    }
#undef SETCOLS

    c0 = sort7(c0); c1 = sort7(c1); c2 = sort7(c2); c3 = sort7(c3);
    c4 = sort7(c4); c5 = sort7(c5); c6 = sort7(c6); c7 = sort7(c7);
    c8 = sort7(c8); c9 = sort7(c9); c10 = sort7(c10); c11 = sort7(c11);
    c12 = sort7(c12); c13 = sort7(c13);

    // ---- group A (px0..3)
    V<28> QA = mrg<14, 14>(mrg<7, 7>(c3, c4), mrg<7, 7>(c5, c6));
    V<14> P12 = mrg<7, 7>(c1, c2);
    V<42> QPA12 = mrg<28, 14>(QA, P12);
    float m0 = sel8(QPA12, c0);
    float m1 = sel8(QPA12, c7);
    V<14> P78 = mrg<7, 7>(c7, c8);
    V<42> QPA78 = mrg<28, 14>(QA, P78);
    float m2 = sel8(QPA78, c2);
    float m3 = sel8(QPA78, c9);

    // ---- group B (px4..7)
    V<28> QB = mrg<14, 14>(mrg<7, 7>(c7, c8), mrg<7, 7>(c9, c10));
    V<14> P56 = mrg<7, 7>(c5, c6);
    V<42> QPB56 = mrg<28, 14>(QB, P56);
    float m4 = sel8(QPB56, c4);
    float m5 = sel8(QPB56, c11);
    V<14> P1112 = mrg<7, 7>(c11, c12);
    V<42> QPB1112 = mrg<28, 14>(QB, P1112);
    float m6 = sel8(QPB1112, c6);
    float m7 = sel8(QPB1112, c13);

    float* op = out + (size_t)r * W + x0;
    float4 o1, o2;
    o1.x = __builtin_amdgcn_fmed3f(m0, 0.0f, 1.0f);
    o1.y = __builtin_amdgcn_fmed3f(m1, 0.0f, 1.0f);
    o1.z = __builtin_amdgcn_fmed3f(m2, 0.0f, 1.0f);
    o1.w = __builtin_amdgcn_fmed3f(m3, 0.0f, 1.0f);
    o2.x = __builtin_amdgcn_fmed3f(m4, 0.0f, 1.0f);
    o2.y = __builtin_amdgcn_fmed3f(m5, 0.0f, 1.0f);
    o2.z = __builtin_amdgcn_fmed3f(m6, 0.0f, 1.0f);
    o2.w = __builtin_amdgcn_fmed3f(m7, 0.0f, 1.0f);
    *reinterpret_cast<float4*>(op) = o1;
    *reinterpret_cast<float4*>(op + 4) = o2;
}

extern "C" void kernel_launch(void* const* d_in, const int* in_sizes, int n_in,
                              void* d_out, int out_size, void* d_ws, size_t ws_size,
                              hipStream_t stream) {
    const float* x = (const float*)d_in[0];
    float* outp = (float*)d_out;
    int rows_total = out_size / W;      // 12288
    int blocks = rows_total / 2;        // 6144 (2 rows per 128-thread block)
    median7_hardtanh_kernel<<<blocks, 128, 0, stream>>>(x, outp);
}